// Round 3
// baseline (408.509 us; speedup 1.0000x reference)
//
#include <hip/hip_runtime.h>
#include <math.h>

#ifndef M_PI
#define M_PI 3.14159265358979323846
#endif

// Problem constants (fixed by reference: x shape (32, 2048, 512) fp32)
constexpr int cB = 32;
constexpr int cT = 2048;
constexpr int cD = 512;
constexpr int cK = 16;

// LDS padding for float2 elements: +1 per 16 -> butterfly passes conflict-free
__device__ __forceinline__ int PZ(int i) { return i + (i >> 4); }

// Twiddle access: table holds e in [0,512); tw(e+512) = tw(e) * (-i)
__device__ __forceinline__ float2 twLO(const float2* TW, int e) {
  return TW[PZ(e)];
}
__device__ __forceinline__ float2 twHI(const float2* TW, int e) {
  float2 w = TW[PZ(e - 512)];
  return make_float2(w.y, -w.x);
}
__device__ __forceinline__ float2 twDYN(const float2* TW, int e) {
  float2 w = TW[PZ(e & 511)];
  return (e < 512) ? w : make_float2(w.y, -w.x);
}

// complex butterfly on float2 registers: a' = a+b; b' = (a-b)*w
__device__ __forceinline__ void bfly(float2& a, float2& b, float wx, float wy) {
  const float tr = a.x - b.x, ti = a.y - b.y;
  a.x += b.x; a.y += b.y;
  b.x = tr * wx - ti * wy;
  b.y = tr * wy + ti * wx;
}

// ---------------------------------------------------------------------------
// Fused 3-stage fp32 DIF pass on float2 LDS: 8 complex/thread, stride S.
// Covers stage halves 4S, 2S, S. O < S holds for all call sites, so
// twiddle site1/site2 high-half selection is static; site3 is DYN.
// ---------------------------------------------------------------------------
template <int S>
__device__ __forceinline__ void pass8(float2* Z, const float2* TW, int B0, int O) {
  float vr[8], vi[8];
#pragma unroll
  for (int m = 0; m < 8; ++m) {
    const float2 z = Z[PZ(B0 + S * m)];
    vr[m] = z.x; vi[m] = z.y;
  }
  constexpr int E1 = 1024 / (4 * S);
  constexpr int E2 = 1024 / (2 * S);
  constexpr int E3 = 1024 / S;
  // stage h = 4S: pairs (m, m+4), e1 = O*E1 + 256*m (static LO/HI per m)
#pragma unroll
  for (int m = 0; m < 4; ++m) {
    const int e = (O + S * m) * E1;
    const float2 w = (m < 2) ? twLO(TW, e) : twHI(TW, e);
    const float ar = vr[m], ai = vi[m], br = vr[m + 4], bi = vi[m + 4];
    vr[m] = ar + br; vi[m] = ai + bi;
    const float tr = ar - br, ti = ai - bi;
    vr[m + 4] = tr * w.x - ti * w.y; vi[m + 4] = tr * w.y + ti * w.x;
  }
  // stage h = 2S: pairs (m, m+2), e2 = O*E2 + 512*m2 (static per m2)
#pragma unroll
  for (int q = 0; q < 8; q += 4) {
#pragma unroll
    for (int m2 = 0; m2 < 2; ++m2) {
      const int m = q + m2;
      const int e = (O + S * m2) * E2;
      const float2 w = (m2 == 0) ? twLO(TW, e) : twHI(TW, e);
      const float ar = vr[m], ai = vi[m], br = vr[m + 2], bi = vi[m + 2];
      vr[m] = ar + br; vi[m] = ai + bi;
      const float tr = ar - br, ti = ai - bi;
      vr[m + 2] = tr * w.x - ti * w.y; vi[m + 2] = tr * w.y + ti * w.x;
    }
  }
  // stage h = S: pairs (m, m+1), e3 = O*E3 (runtime high/low unless O==0)
  {
    const int e = O * E3;
    const float2 w = (S == 1) ? twLO(TW, 0) : twDYN(TW, e);
#pragma unroll
    for (int m = 0; m < 8; m += 2) {
      const float ar = vr[m], ai = vi[m], br = vr[m + 1], bi = vi[m + 1];
      vr[m] = ar + br; vi[m] = ai + bi;
      const float tr = ar - br, ti = ai - bi;
      vr[m + 1] = tr * w.x - ti * w.y; vi[m + 1] = tr * w.y + ti * w.x;
    }
  }
#pragma unroll
  for (int m = 0; m < 8; ++m) Z[PZ(B0 + S * m)] = make_float2(vr[m], vi[m]);
}

// ---------------------------------------------------------------------------
// Fully fused kernel: gather 2 columns from x (B,T,D) -> 2048-pt FFT (two
// real columns packed complex) -> Hermitian top-16 selection (fp64 boundary
// refinement) -> params broadcast in LDS -> direct reconstruction of
// y[b, :, d0:d0+2] via step-256 Chebyshev recurrence. One kernel, no global
// intermediates.
// Block-index swizzle groups the 16 blocks sharing each 128-B line (32
// consecutive d) onto the SAME XCD with adjacent dispatch IDs: x-lines are
// fetched once into that XCD's L2 and served 16x; y-lines aggregate their
// 16 partial writes in the same L2.
// ---------------------------------------------------------------------------
__global__ __launch_bounds__(256) void k_fused(const float* __restrict__ x,
                                               float* __restrict__ y) {
  __shared__ float2 Z[2176];    // padded 2048 complex
  __shared__ float2 TW[544];    // padded 512 twiddles
  __shared__ float4 CVq[32];    // candidate values (as float[128]) / params
  __shared__ int    CK[128];
  __shared__ int    CC[4];      // per-wave candidate counts
  float* CV = (float*)CVq;      // harvest/merge view
  float4* PRM = CVq;            // post-merge param view (aliased; safe: all
                                // CV reads precede PRM writes in-wave)

  const int tid   = threadIdx.x;
  const int lane  = tid & 63;
  const int wave  = tid >> 6;

  // --- XCD-aware block swizzle: HW assigns XCD = blockIdx.x % 8 (round
  // robin). Map so the 16 blocks of one "line group" (d in [32m, 32m+32))
  // share one XCD and are dispatched within a 128-wide ID window.
  const int i_  = blockIdx.x;
  const int c_  = i_ & 7;            // XCD
  const int j_  = i_ >> 3;           // 0..511
  const int G_  = c_ * 64 + (j_ >> 4);   // group 0..511
  const int s_  = j_ & 15;
  const int b     = G_ >> 4;             // 0..31
  const int dpair = ((G_ & 15) << 4) | s_;  // 0..255
  const int d0    = dpair * 2;

  // --- gather the two columns as float2 (d0,d0+1 adjacent), 8 rows/thread.
  // Issue all loads first; twiddle sincos below hides the latency.
  const float2* xp = (const float2*)x + (size_t)b * cT * (cD / 2) + dpair;
  float2 vv[8];
#pragma unroll
  for (int u = 0; u < 8; ++u) {
    vv[u] = xp[(size_t)(tid + 256 * u) * (cD / 2)];
  }

  // Twiddles: TW[j] = exp(-2*pi*i*j/2048), j in [0,512)
  for (int j = tid; j < 512; j += 256) {
    float s, c;
    __sincosf(-2.0f * (float)M_PI * (float)j * (1.0f / 2048.0f), &s, &c);
    TW[PZ(j)] = make_float2(c, s);
  }

  // --- Pass A in REGISTERS: stages h=1024, 512. vv[u] holds t = tid+256u,
  // so group u (O = tid+256u) has inputs vv[u+2m], m=0..3. Twiddles direct.
#pragma unroll
  for (int u = 0; u < 2; ++u) {
    const int O = tid + 256 * u;
    float s1, c1, s2, c2;
    __sincosf(-2.0f * (float)M_PI * (float)O * (1.0f / 2048.0f), &s1, &c1);
    __sincosf(-2.0f * (float)M_PI * (float)(2 * O) * (1.0f / 2048.0f), &s2, &c2);
    // h=1024: pairs (m,m+2): m=0 w=tw(O); m=1 w=tw(O+512)=tw(O)*(-i)
    bfly(vv[u],     vv[u + 4], c1, s1);
    bfly(vv[u + 2], vv[u + 6], s1, -c1);
    // h=512: pairs (m,m+1), both use w=tw(2O)
    bfly(vv[u],     vv[u + 2], c2, s2);
    bfly(vv[u + 4], vv[u + 6], c2, s2);
    Z[PZ(O)]        = vv[u];
    Z[PZ(O + 512)]  = vv[u + 2];
    Z[PZ(O + 1024)] = vv[u + 4];
    Z[PZ(O + 1536)] = vv[u + 6];
  }
  __syncthreads();

  pass8<64>(Z, TW, (tid >> 6) * 512 + (tid & 63), tid & 63);
  __syncthreads();
  pass8<8>(Z, TW, (tid >> 3) * 64 + (tid & 7), tid & 7);
  __syncthreads();
  pass8<1>(Z, TW, tid * 8, 0);
  __syncthreads();
  // X[k] sits at Z[PZ(bitrev11(k))]

  // --- Hermitian split + |2X|^2 into registers: wave -> 512 bins, one column
  const int col  = wave >> 1;
  const int half = wave & 1;
  float v[8];
  int   kk[8];
#pragma unroll
  for (int u = 0; u < 8; ++u) {
    const int k = half * 512 + lane + 64 * u;  // 0..1023
    kk[u] = k;
    if (k == 0) { v[u] = -1.0f; continue; }
    const float2 p = Z[PZ((int)(__brev((unsigned)k) >> 21))];
    const float2 q = Z[PZ((int)(__brev((unsigned)(2048 - k)) >> 21))];
    float xr, xi;
    if (col == 0) { xr = p.x + q.x; xi = p.y - q.y; }   // 2*X_a[k]
    else          { xr = p.y + q.y; xi = q.x - p.x; }   // 2*X_b[k]
    v[u] = xr * xr + xi * xi;
  }

  // --- per-wave candidate harvest via lane-max threshold (O(log^2)).
  //     thr = 17th-largest of the 64 lane maxima. Any bin < thr has >=17
  //     larger bins in this wave alone -> can never be in the column top-17.
  {
    float lm = v[0];
#pragma unroll
    for (int j = 1; j < 8; ++j) lm = fmaxf(lm, v[j]);
    // values-only bitonic sort, descending across 64 lanes
    float sm = lm;
#pragma unroll
    for (int k2 = 2; k2 <= 64; k2 <<= 1) {
#pragma unroll
      for (int j = k2 >> 1; j > 0; j >>= 1) {
        const float om = __shfl_xor(sm, j);
        const bool wmin = ((lane & k2) == 0) != ((lane & j) == 0);
        const bool oless = (om < sm);
        sm = (oless == wmin) ? om : sm;
      }
    }
    const float thr = __shfl(sm, 16);   // 17th largest lane-max (rank 16)

    unsigned long long mball[8];
    int cnt = 0;
#pragma unroll
    for (int j = 0; j < 8; ++j) {
      mball[j] = __ballot(v[j] >= thr);
      cnt += __popcll(mball[j]);
    }

    if (cnt <= 32) {
      // ballot-prefix compaction into this wave's 32 slots
      int pos = 0;
#pragma unroll
      for (int j = 0; j < 8; ++j) {
        const int p = pos + __popcll(mball[j] & ((1ull << lane) - 1ull));
        if (v[j] >= thr) { CV[wave * 32 + p] = v[j]; CK[wave * 32 + p] = kk[j]; }
        pos += __popcll(mball[j]);
      }
      if (lane == 0) CC[wave] = cnt;
    } else {
      // statistically-never fallback: original exact 17-round extraction
      float fv[8];
#pragma unroll
      for (int j = 0; j < 8; ++j) fv[j] = v[j];
      for (int it = 0; it < cK + 1; ++it) {
        float bv = fv[0]; int bj = 0;
#pragma unroll
        for (int j = 1; j < 8; ++j) if (fv[j] > bv) { bv = fv[j]; bj = j; }
        int bk = kk[bj];
        for (int off = 32; off > 0; off >>= 1) {
          const float ov = __shfl_down(bv, off);
          const int   ok = __shfl_down(bk, off);
          if (ov > bv) { bv = ov; bk = ok; }
        }
        const int   bkb = __shfl(bk, 0);
        const float bvb = __shfl(bv, 0);
#pragma unroll
        for (int j = 0; j < 8; ++j) if (kk[j] == bkb) fv[j] = -1.0f;
        if (lane == 0) { CV[wave * 32 + it] = bvb; CK[wave * 32 + it] = bkb; }
      }
      if (lane == 0) CC[wave] = cK + 1;
    }
  }
  __syncthreads();

  // --- merge per column (waves 0 and 2): one bitonic sort of <=64 candidates
  if ((wave & 1) == 0) {
    const int c0 = CC[wave];
    const int c1 = CC[wave + 1];
    const int n  = c0 + c1;            // in [34, 64]
    float mv = -1.0f;
    int   mk = 5000 + lane;            // distinct pad keys; sink below reals
    if (lane < c0)     { mv = CV[wave * 32 + lane];            mk = CK[wave * 32 + lane]; }
    else if (lane < n) { mv = CV[(wave + 1) * 32 + lane - c0]; mk = CK[(wave + 1) * 32 + lane - c0]; }

    // bitonic sort descending by v, tie -> smaller k first (strict total
    // order: no payload loss possible even under exact fp32 ties)
#pragma unroll
    for (int k2 = 2; k2 <= 64; k2 <<= 1) {
#pragma unroll
      for (int j = k2 >> 1; j > 0; j >>= 1) {
        const float ov = __shfl_xor(mv, j);
        const int   ok = __shfl_xor(mk, j);
        const bool wmin  = ((lane & k2) == 0) != ((lane & j) == 0);
        const bool oless = (ov < mv) || (ov == mv && ok > mk);
        if (oless == wmin) { mv = ov; mk = ok; }
      }
    }
    const float myv = mv;  // lane i holds rank-i (descending)
    const int   myk = mk;

    // --- boundary check: rank-15 (last in) vs rank-16 (first out)
    const float v15 = __shfl(myv, 15);
    const float v16 = __shfl(myv, 16);
    const int   k15 = __shfl(myk, 15);
    const int   k16 = __shfl(myk, 16);
    bool  do_swap = false;
    double aR = 0.0, pR = 0.0;
    if (v15 - v16 < 1e-3f * v15) {
      // fp64 direct DFT of the two boundary bins (exact vs numpy).
      // Reads x strided (rare path, lines likely still in L2).
      const float* colp = x + (size_t)b * cT * cD + (d0 + col);
      double m2[2], XR[2], XI[2];
      for (int bb = 0; bb < 2; ++bb) {
        const int k = bb ? k16 : k15;
        double sr = 0.0, si = 0.0;
        for (int u = 0; u < 32; ++u) {
          const int t = lane + 64 * u;
          const int m = (k * t) & 2047;
          double s, c;
          sincos(-M_PI * (double)m / 1024.0, &s, &c);
          const double xv = (double)colp[(size_t)t * cD];
          sr += xv * c; si += xv * s;
        }
        for (int off = 32; off > 0; off >>= 1) {
          sr += __shfl_down(sr, off);
          si += __shfl_down(si, off);
        }
        sr = __shfl(sr, 0); si = __shfl(si, 0);
        m2[bb] = sr * sr + si * si; XR[bb] = sr; XI[bb] = si;
      }
      if (m2[1] > m2[0]) {
        do_swap = true;
        aR = sqrt(m2[1]);
        pR = atan2(XI[1], XR[1]);
      }
    }

    if (lane < cK) {
      float a, p, kf;
      if (do_swap && lane == 15) {
        a = (float)aR; p = (float)pR; kf = (float)k16;
      } else {
        const int k = myk;
        const float2 zp = Z[PZ((int)(__brev((unsigned)k) >> 21))];
        const float2 zq = Z[PZ((int)(__brev((unsigned)(2048 - k)) >> 21))];
        float xr, xi;
        if (col == 0) { xr = 0.5f * (zp.x + zq.x); xi = 0.5f * (zp.y - zq.y); }
        else          { xr = 0.5f * (zp.y + zq.y); xi = 0.5f * (zq.x - zp.x); }
        a = sqrtf(xr * xr + xi * xi);
        p = atan2f(xi, xr);
        kf = (float)k;
      }
      // params to LDS only (aliased over dead CV space; our reads are done)
      PRM[col * cK + lane] = make_float4(a, kf, p, 0.0f);
    }
  }
  __syncthreads();

  // --- reconstruction: thread handles t = tid + 256n (n=0..7), both columns.
  // y(t) = sum_j a_j cos(w_j t + p_j), w_j = kf_j * Cw. Step-256 Chebyshev:
  // y_{n+1} = 2cos(256 w) y_n - y_{n-1}; integer products kf*t < 2^21 exact.
  {
    const float Cw = (float)(2.0 * M_PI / (2047.0 * 2048.0));
    const float tf = (float)tid;
    float accA[8], accB[8];
#pragma unroll
    for (int n = 0; n < 8; ++n) { accA[n] = 0.0f; accB[n] = 0.0f; }

#define RECON_COL(ACC, CBASE)                                              \
    _Pragma("unroll")                                                      \
    for (int j = 0; j < cK; ++j) {                                         \
      const float4 pr = PRM[(CBASE) + j];                                  \
      const float aj = pr.x, kj = pr.y, pj = pr.z;                         \
      const float kt0  = kj * tf;       /* exact: < 2^18 */                \
      const float k256 = kj * 256.0f;   /* exact: < 2^18 */                \
      float y0 = aj * __cosf(__fmaf_rn(kt0, Cw, pj));                      \
      float y1 = aj * __cosf(__fmaf_rn(kt0 + k256, Cw, pj));               \
      const float cm2 = 2.0f * __cosf(k256 * Cw);                          \
      ACC[0] += y0; ACC[1] += y1;                                          \
      _Pragma("unroll")                                                    \
      for (int n = 2; n < 8; ++n) {                                        \
        const float y2 = __fmaf_rn(cm2, y1, -y0);                          \
        ACC[n] += y2; y0 = y1; y1 = y2;                                    \
      }                                                                    \
    }

    RECON_COL(accA, 0)
    RECON_COL(accB, cK)
#undef RECON_COL

    float2* yp = (float2*)y + ((size_t)b * cT + tid) * (cD / 2) + dpair;
#pragma unroll
    for (int n = 0; n < 8; ++n) {
      yp[(size_t)(256 * n) * (cD / 2)] = make_float2(accA[n], accB[n]);
    }
  }
}

// ---------------------------------------------------------------------------
extern "C" void kernel_launch(void* const* d_in, const int* in_sizes, int n_in,
                              void* d_out, int out_size, void* d_ws, size_t ws_size,
                              hipStream_t stream) {
  const float* x = (const float*)d_in[0];
  float* out = (float*)d_out;
  (void)d_ws; (void)ws_size;

  k_fused<<<cB * cD / 2, 256, 0, stream>>>(x, out);
}

// Round 4
// 333.998 us; speedup vs baseline: 1.2231x; 1.2231x over previous
//
#include <hip/hip_runtime.h>
#include <math.h>

#ifndef M_PI
#define M_PI 3.14159265358979323846
#endif

// Problem constants (fixed by reference: x shape (32, 2048, 512) fp32)
constexpr int cB = 32;
constexpr int cT = 2048;
constexpr int cD = 512;
constexpr int cK = 16;
constexpr int TCH = 64;

// LDS padding for float2 elements: +1 per 16 -> butterfly passes conflict-free
__device__ __forceinline__ int PZ(int i) { return i + (i >> 4); }

// Twiddle access: table holds e in [0,512); tw(e+512) = tw(e) * (-i)
__device__ __forceinline__ float2 twLO(const float2* TW, int e) {
  return TW[PZ(e)];
}
__device__ __forceinline__ float2 twHI(const float2* TW, int e) {
  float2 w = TW[PZ(e - 512)];
  return make_float2(w.y, -w.x);
}
__device__ __forceinline__ float2 twDYN(const float2* TW, int e) {
  float2 w = TW[PZ(e & 511)];
  return (e < 512) ? w : make_float2(w.y, -w.x);
}

// complex butterfly on float2 registers: a' = a+b; b' = (a-b)*w
__device__ __forceinline__ void bfly(float2& a, float2& b, float wx, float wy) {
  const float tr = a.x - b.x, ti = a.y - b.y;
  a.x += b.x; a.y += b.y;
  b.x = tr * wx - ti * wy;
  b.y = tr * wy + ti * wx;
}

// Wave-local LDS fence: drains this wave's LDS writes so its own lanes can
// read them. Valid replacement for __syncthreads() ONLY when producer and
// consumer are the same wave (pass8 chunks are wave-private; see call sites).
__device__ __forceinline__ void wave_lds_fence() {
  asm volatile("s_waitcnt lgkmcnt(0)" ::: "memory");
  __builtin_amdgcn_sched_barrier(0);
}

// ---------------------------------------------------------------------------
// Fused 3-stage fp32 DIF pass on float2 LDS: 8 complex/thread, stride S.
// Covers stage halves 4S, 2S, S. O < S holds for all call sites, so
// twiddle site1/site2 high-half selection is static; site3 is DYN.
// All indices touched lie in [wave*512, wave*512+512) for every call site,
// so no cross-wave synchronization is required between passes.
// ---------------------------------------------------------------------------
template <int S>
__device__ __forceinline__ void pass8(float2* Z, const float2* TW, int B0, int O) {
  float vr[8], vi[8];
#pragma unroll
  for (int m = 0; m < 8; ++m) {
    const float2 z = Z[PZ(B0 + S * m)];
    vr[m] = z.x; vi[m] = z.y;
  }
  constexpr int E1 = 1024 / (4 * S);
  constexpr int E2 = 1024 / (2 * S);
  constexpr int E3 = 1024 / S;
  // stage h = 4S: pairs (m, m+4), e1 = O*E1 + 256*m (static LO/HI per m)
#pragma unroll
  for (int m = 0; m < 4; ++m) {
    const int e = (O + S * m) * E1;
    const float2 w = (m < 2) ? twLO(TW, e) : twHI(TW, e);
    const float ar = vr[m], ai = vi[m], br = vr[m + 4], bi = vi[m + 4];
    vr[m] = ar + br; vi[m] = ai + bi;
    const float tr = ar - br, ti = ai - bi;
    vr[m + 4] = tr * w.x - ti * w.y; vi[m + 4] = tr * w.y + ti * w.x;
  }
  // stage h = 2S: pairs (m, m+2), e2 = O*E2 + 512*m2 (static per m2)
#pragma unroll
  for (int q = 0; q < 8; q += 4) {
#pragma unroll
    for (int m2 = 0; m2 < 2; ++m2) {
      const int m = q + m2;
      const int e = (O + S * m2) * E2;
      const float2 w = (m2 == 0) ? twLO(TW, e) : twHI(TW, e);
      const float ar = vr[m], ai = vi[m], br = vr[m + 2], bi = vi[m + 2];
      vr[m] = ar + br; vi[m] = ai + bi;
      const float tr = ar - br, ti = ai - bi;
      vr[m + 2] = tr * w.x - ti * w.y; vi[m + 2] = tr * w.y + ti * w.x;
    }
  }
  // stage h = S: pairs (m, m+1), e3 = O*E3 (runtime high/low unless O==0)
  {
    const int e = O * E3;
    const float2 w = (S == 1) ? twLO(TW, 0) : twDYN(TW, e);
#pragma unroll
    for (int m = 0; m < 8; m += 2) {
      const float ar = vr[m], ai = vi[m], br = vr[m + 1], bi = vi[m + 1];
      vr[m] = ar + br; vi[m] = ai + bi;
      const float tr = ar - br, ti = ai - bi;
      vr[m + 1] = tr * w.x - ti * w.y; vi[m + 1] = tr * w.y + ti * w.x;
    }
  }
#pragma unroll
  for (int m = 0; m < 8; ++m) Z[PZ(B0 + S * m)] = make_float2(vr[m], vi[m]);
}

// ---------------------------------------------------------------------------
// Kernel 1: fp32 2048-pt DIF FFT of two packed real columns, gathered
// DIRECTLY from x (B,T,D). Columns d0,d0+1 adjacent: one float2/row at 2KB
// stride. Block-index swizzle groups the 16 blocks sharing each 128-B line
// (32 consecutive d) onto the SAME XCD with adjacent dispatch IDs -> x-lines
// fetched once into L2, served 16x. Pass A (h=1024,512) in registers on the
// gathered values; passes B/C/D are wave-private LDS chunks (no barriers
// between them, only wave-local lgkmcnt fences). Selection: per-wave lane-max
// threshold + ballot compaction, per-column 64-lane bitonic merge; fp64
// direct-DFT refinement of the rank-15/16 boundary (rare path).
// ---------------------------------------------------------------------------
__global__ __launch_bounds__(256) void k_fft_topk(const float* __restrict__ x,
                                                  float* __restrict__ amp_out,
                                                  float* __restrict__ kf_out,
                                                  float* __restrict__ ph_out) {
  __shared__ float2 Z[2176];    // padded 2048 complex
  __shared__ float2 TW[544];    // padded 512 twiddles
  __shared__ float  CV[128];    // 4 waves x 32 candidate slots
  __shared__ int    CK[128];
  __shared__ int    CC[4];      // per-wave candidate counts

  const int tid   = threadIdx.x;
  const int lane  = tid & 63;
  const int wave  = tid >> 6;

  // --- XCD-aware block swizzle (HW: XCD = blockIdx.x % 8 round robin)
  const int i_  = blockIdx.x;
  const int c_  = i_ & 7;            // XCD
  const int j_  = i_ >> 3;           // 0..511
  const int G_  = c_ * 64 + (j_ >> 4);   // group 0..511
  const int s_  = j_ & 15;
  const int b     = G_ >> 4;             // 0..31
  const int dpair = ((G_ & 15) << 4) | s_;  // 0..255
  const int d0    = dpair * 2;

  // --- gather the two columns as float2 (d0,d0+1 adjacent), 8 rows/thread.
  const float2* xp = (const float2*)x + (size_t)b * cT * (cD / 2) + dpair;
  float2 vv[8];
#pragma unroll
  for (int u = 0; u < 8; ++u) {
    vv[u] = xp[(size_t)(tid + 256 * u) * (cD / 2)];
  }

  // Twiddles: TW[j] = exp(-2*pi*i*j/2048), j in [0,512)
  for (int j = tid; j < 512; j += 256) {
    float s, c;
    __sincosf(-2.0f * (float)M_PI * (float)j * (1.0f / 2048.0f), &s, &c);
    TW[PZ(j)] = make_float2(c, s);
  }

  // --- Pass A in REGISTERS: stages h=1024, 512. vv[u] holds t = tid+256u;
  // group u (O = tid+256u) has inputs vv[u+2m], m=0..3. Twiddles direct.
#pragma unroll
  for (int u = 0; u < 2; ++u) {
    const int O = tid + 256 * u;
    float s1, c1, s2, c2;
    __sincosf(-2.0f * (float)M_PI * (float)O * (1.0f / 2048.0f), &s1, &c1);
    __sincosf(-2.0f * (float)M_PI * (float)(2 * O) * (1.0f / 2048.0f), &s2, &c2);
    // h=1024: pairs (m,m+2): m=0 w=tw(O); m=1 w=tw(O+512)=tw(O)*(-i)
    bfly(vv[u],     vv[u + 4], c1, s1);
    bfly(vv[u + 2], vv[u + 6], s1, -c1);
    // h=512: pairs (m,m+1), both use w=tw(2O)
    bfly(vv[u],     vv[u + 2], c2, s2);
    bfly(vv[u + 4], vv[u + 6], c2, s2);
    Z[PZ(O)]        = vv[u];
    Z[PZ(O + 512)]  = vv[u + 2];
    Z[PZ(O + 1024)] = vv[u + 4];
    Z[PZ(O + 1536)] = vv[u + 6];
  }
  __syncthreads();   // Pass A writes cross wave chunks; TW must be visible

  // Passes B/C/D: each wave owns Z chunk [wave*512, wave*512+512) in all
  // three — only wave-local LDS fences needed between them.
  pass8<64>(Z, TW, (tid >> 6) * 512 + (tid & 63), tid & 63);
  wave_lds_fence();
  pass8<8>(Z, TW, (tid >> 3) * 64 + (tid & 7), tid & 7);
  wave_lds_fence();
  pass8<1>(Z, TW, tid * 8, 0);
  __syncthreads();   // harvest reads bit-reversed indices across all chunks
  // X[k] sits at Z[PZ(bitrev11(k))]

  // --- Hermitian split + |2X|^2 into registers: wave -> 512 bins, one column
  const int col  = wave >> 1;
  const int half = wave & 1;
  float v[8];
  int   kk[8];
#pragma unroll
  for (int u = 0; u < 8; ++u) {
    const int k = half * 512 + lane + 64 * u;  // 0..1023
    kk[u] = k;
    if (k == 0) { v[u] = -1.0f; continue; }
    const float2 p = Z[PZ((int)(__brev((unsigned)k) >> 21))];
    const float2 q = Z[PZ((int)(__brev((unsigned)(2048 - k)) >> 21))];
    float xr, xi;
    if (col == 0) { xr = p.x + q.x; xi = p.y - q.y; }   // 2*X_a[k]
    else          { xr = p.y + q.y; xi = q.x - p.x; }   // 2*X_b[k]
    v[u] = xr * xr + xi * xi;
  }

  // --- per-wave candidate harvest via lane-max threshold (O(log^2)).
  //     thr = 17th-largest of the 64 lane maxima. Any bin < thr has >=17
  //     larger bins in this wave alone -> can never be in the column top-17.
  {
    float lm = v[0];
#pragma unroll
    for (int j = 1; j < 8; ++j) lm = fmaxf(lm, v[j]);
    // values-only bitonic sort, descending across 64 lanes
    float sm = lm;
#pragma unroll
    for (int k2 = 2; k2 <= 64; k2 <<= 1) {
#pragma unroll
      for (int j = k2 >> 1; j > 0; j >>= 1) {
        const float om = __shfl_xor(sm, j);
        const bool wmin = ((lane & k2) == 0) != ((lane & j) == 0);
        const bool oless = (om < sm);
        sm = (oless == wmin) ? om : sm;
      }
    }
    const float thr = __shfl(sm, 16);   // 17th largest lane-max (rank 16)

    unsigned long long mball[8];
    int cnt = 0;
#pragma unroll
    for (int j = 0; j < 8; ++j) {
      mball[j] = __ballot(v[j] >= thr);
      cnt += __popcll(mball[j]);
    }

    if (cnt <= 32) {
      // ballot-prefix compaction into this wave's 32 slots
      int pos = 0;
#pragma unroll
      for (int j = 0; j < 8; ++j) {
        const int p = pos + __popcll(mball[j] & ((1ull << lane) - 1ull));
        if (v[j] >= thr) { CV[wave * 32 + p] = v[j]; CK[wave * 32 + p] = kk[j]; }
        pos += __popcll(mball[j]);
      }
      if (lane == 0) CC[wave] = cnt;
    } else {
      // statistically-never fallback: original exact 17-round extraction
      float fv[8];
#pragma unroll
      for (int j = 0; j < 8; ++j) fv[j] = v[j];
      for (int it = 0; it < cK + 1; ++it) {
        float bv = fv[0]; int bj = 0;
#pragma unroll
        for (int j = 1; j < 8; ++j) if (fv[j] > bv) { bv = fv[j]; bj = j; }
        int bk = kk[bj];
        for (int off = 32; off > 0; off >>= 1) {
          const float ov = __shfl_down(bv, off);
          const int   ok = __shfl_down(bk, off);
          if (ov > bv) { bv = ov; bk = ok; }
        }
        const int   bkb = __shfl(bk, 0);
        const float bvb = __shfl(bv, 0);
#pragma unroll
        for (int j = 0; j < 8; ++j) if (kk[j] == bkb) fv[j] = -1.0f;
        if (lane == 0) { CV[wave * 32 + it] = bvb; CK[wave * 32 + it] = bkb; }
      }
      if (lane == 0) CC[wave] = cK + 1;
    }
  }
  __syncthreads();

  // --- merge per column (waves 0 and 2): one bitonic sort of <=64 candidates
  if ((wave & 1) == 0) {
    const int c0 = CC[wave];
    const int c1 = CC[wave + 1];
    const int n  = c0 + c1;            // in [34, 64]
    float mv = -1.0f;
    int   mk = 5000 + lane;            // distinct pad keys; sink below reals
    if (lane < c0)     { mv = CV[wave * 32 + lane];            mk = CK[wave * 32 + lane]; }
    else if (lane < n) { mv = CV[(wave + 1) * 32 + lane - c0]; mk = CK[(wave + 1) * 32 + lane - c0]; }

    // bitonic sort descending by v, tie -> smaller k first (strict total
    // order: no payload loss possible even under exact fp32 ties)
#pragma unroll
    for (int k2 = 2; k2 <= 64; k2 <<= 1) {
#pragma unroll
      for (int j = k2 >> 1; j > 0; j >>= 1) {
        const float ov = __shfl_xor(mv, j);
        const int   ok = __shfl_xor(mk, j);
        const bool wmin  = ((lane & k2) == 0) != ((lane & j) == 0);
        const bool oless = (ov < mv) || (ov == mv && ok > mk);
        if (oless == wmin) { mv = ov; mk = ok; }
      }
    }
    const float myv = mv;  // lane i holds rank-i (descending)
    const int   myk = mk;

    // --- boundary check: rank-15 (last in) vs rank-16 (first out)
    const float v15 = __shfl(myv, 15);
    const float v16 = __shfl(myv, 16);
    const int   k15 = __shfl(myk, 15);
    const int   k16 = __shfl(myk, 16);
    bool  do_swap = false;
    double aR = 0.0, pR = 0.0;
    if (v15 - v16 < 1e-3f * v15) {
      // fp64 direct DFT of the two boundary bins (exact vs numpy).
      // Reads x strided (rare path, lines likely still in L2).
      const float* colp = x + (size_t)b * cT * cD + (d0 + col);
      double m2[2], XR[2], XI[2];
      for (int bb = 0; bb < 2; ++bb) {
        const int k = bb ? k16 : k15;
        double sr = 0.0, si = 0.0;
        for (int u = 0; u < 32; ++u) {
          const int t = lane + 64 * u;
          const int m = (k * t) & 2047;
          double s, c;
          sincos(-M_PI * (double)m / 1024.0, &s, &c);
          const double xv = (double)colp[(size_t)t * cD];
          sr += xv * c; si += xv * s;
        }
        for (int off = 32; off > 0; off >>= 1) {
          sr += __shfl_down(sr, off);
          si += __shfl_down(si, off);
        }
        sr = __shfl(sr, 0); si = __shfl(si, 0);
        m2[bb] = sr * sr + si * si; XR[bb] = sr; XI[bb] = si;
      }
      if (m2[1] > m2[0]) {
        do_swap = true;
        aR = sqrt(m2[1]);
        pR = atan2(XI[1], XR[1]);
      }
    }

    if (lane < cK) {
      float a, p, kf;
      if (do_swap && lane == 15) {
        a = (float)aR; p = (float)pR; kf = (float)k16;
      } else {
        const int k = myk;
        const float2 zp = Z[PZ((int)(__brev((unsigned)k) >> 21))];
        const float2 zq = Z[PZ((int)(__brev((unsigned)(2048 - k)) >> 21))];
        float xr, xi;
        if (col == 0) { xr = 0.5f * (zp.x + zq.x); xi = 0.5f * (zp.y - zq.y); }
        else          { xr = 0.5f * (zp.y + zq.y); xi = 0.5f * (zq.x - zp.x); }
        a = sqrtf(xr * xr + xi * xi);
        p = atan2f(xi, xr);
        kf = (float)k;
      }
      const size_t cidx = ((size_t)b * cD + (d0 + col)) * cK + lane;
      amp_out[cidx] = a;
      kf_out[cidx]  = kf;
      ph_out[cidx]  = p;
    }
  }
}

// ---------------------------------------------------------------------------
// Kernel 2: y[b,t,d] = sum_j a_j cos(w_j t + p_j), w_j = 2*pi*k_j/(2048*2047).
// Coupled recurrence: dd += -cm*r; r += dd, cm = w^2(1 - w^2/12); exact
// re-init per 64-t chunk. Stores are d-contiguous (fully coalesced) — this
// is why recon stays a separate kernel (round-3 fusion made stores 8B/2KB
// scatters: +50% WRITE_SIZE, +70 us).
// ---------------------------------------------------------------------------
__global__ __launch_bounds__(256) void k_recon(const float* __restrict__ amp_in,
                                               const float* __restrict__ kf_in,
                                               const float* __restrict__ ph_in,
                                               float* __restrict__ y) {
  const int tid = threadIdx.x;
  const int d   = blockIdx.y * 256 + tid;
  const int b   = blockIdx.z;
  const int t0  = blockIdx.x * TCH;
  const size_t cidx = ((size_t)b * cD + d) * cK;
  const float Cw = (float)(2.0 * M_PI / (2047.0 * 2048.0));
  const float t0f = (float)t0;

  // vectorized param loads (cK = 16 -> 4 float4 per array)
  float amp[cK], kf[cK], ph[cK];
#pragma unroll
  for (int q = 0; q < 4; ++q) {
    const float4 va = ((const float4*)(amp_in + cidx))[q];
    const float4 vk = ((const float4*)(kf_in + cidx))[q];
    const float4 vp = ((const float4*)(ph_in + cidx))[q];
    amp[4*q+0] = va.x; amp[4*q+1] = va.y; amp[4*q+2] = va.z; amp[4*q+3] = va.w;
    kf [4*q+0] = vk.x; kf [4*q+1] = vk.y; kf [4*q+2] = vk.z; kf [4*q+3] = vk.w;
    ph [4*q+0] = vp.x; ph [4*q+1] = vp.y; ph [4*q+2] = vp.z; ph [4*q+3] = vp.w;
  }

  float r[cK], dd[cK], cm[cK];
  float acc0 = 0.0f, acc1 = 0.0f;
#pragma unroll
  for (int j = 0; j < cK; ++j) {
    const float w  = kf[j] * Cw;
    const float w2 = w * w;
    cm[j] = w2 - w2 * w2 * (1.0f / 12.0f);
    const float kt = kf[j] * t0f;          // exact: k*t < 2^21
    const float r0 = amp[j] * __cosf(__fmaf_rn(kt, Cw, ph[j]));
    const float r1 = amp[j] * __cosf(__fmaf_rn(kt + kf[j], Cw, ph[j]));
    r[j] = r1; dd[j] = r1 - r0;
    acc0 += r0; acc1 += r1;
  }
  float* yp = y + ((size_t)b * cT + t0) * cD + d;
  yp[0] = acc0;
  yp[cD] = acc1;
  yp += 2 * (size_t)cD;
#pragma unroll 2
  for (int t = 2; t < TCH; ++t) {
    float acc = 0.0f;
#pragma unroll
    for (int j = 0; j < cK; ++j) {
      dd[j] = __fmaf_rn(-cm[j], r[j], dd[j]);
      r[j] += dd[j];
      acc += r[j];
    }
    *yp = acc;
    yp += cD;
  }
}

// ---------------------------------------------------------------------------
extern "C" void kernel_launch(void* const* d_in, const int* in_sizes, int n_in,
                              void* d_out, int out_size, void* d_ws, size_t ws_size,
                              hipStream_t stream) {
  const float* x = (const float*)d_in[0];
  float* out = (float*)d_out;

  float* amp = (float*)d_ws;
  float* kf  = amp + (size_t)cB * cD * cK;
  float* ph  = kf + (size_t)cB * cD * cK;

  k_fft_topk<<<cB * cD / 2, 256, 0, stream>>>(x, amp, kf, ph);

  dim3 g3(cT / TCH, cD / 256, cB), b3(256, 1, 1);
  k_recon<<<g3, b3, 0, stream>>>(amp, kf, ph, out);
}